// Round 1
// baseline (6891.282 us; speedup 1.0000x reference)
//
#include <hip/hip_runtime.h>
#include <math.h>

#define NN 3072
#define NW 96            // NN/32 packed words per column
#define EPSG 1e-20f

// ---------- prep kernel 1: rowsum0[i] = sum_c adj[i][c] ----------
__global__ __launch_bounds__(256) void rowsum_kernel(const float* __restrict__ adj,
                                                     float* __restrict__ rowsum) {
    int row = blockIdx.x;
    const float* r = adj + (size_t)row * NN;
    float s = 0.f;
    for (int c = threadIdx.x; c < NN; c += 256) s += r[c];
#pragma unroll
    for (int off = 32; off > 0; off >>= 1) s += __shfl_down(s, off);
    __shared__ float ps[4];
    if ((threadIdx.x & 63) == 0) ps[threadIdx.x >> 6] = s;
    __syncthreads();
    if (threadIdx.x == 0) rowsum[row] = (ps[0] + ps[1]) + (ps[2] + ps[3]);
}

// ---------- prep kernel 2: packedT[c][w] bit k = (adj[32w+k][c] != 0) ----------
__global__ __launch_bounds__(256) void pack_kernel(const float* __restrict__ adj,
                                                   unsigned* __restrict__ packedT) {
    int c = blockIdx.x * 256 + threadIdx.x;   // column index (12 blocks in x)
    int w = blockIdx.y;                        // word index 0..95
    const float* base = adj + (size_t)(w * 32) * NN + c;
    unsigned bits = 0u;
#pragma unroll
    for (int k = 0; k < 32; ++k)
        bits |= (base[(size_t)k * NN] != 0.0f) ? (1u << k) : 0u;
    packedT[(size_t)c * NW + w] = bits;
}

// ---------- sequential topo-sort kernel: single block ----------
__global__ __launch_bounds__(1024) void topo_kernel(const float* __restrict__ logits,
                                                    const float* __restrict__ unif,
                                                    const float* __restrict__ rowsum0,
                                                    const unsigned* __restrict__ packedT,
                                                    float* __restrict__ out) {
    __shared__ float s_row[NN];    // running rowsum; -1 sentinel when selected
    __shared__ float s_gum[NN];    // gumbel logits
    __shared__ float s_elog[NN];   // exp(logits)
    __shared__ float s_logit[NN];  // raw logits
    __shared__ float red_val[16];
    __shared__ float red_sum[16];
    __shared__ int   red_idx[16];
    __shared__ int   s_sel;

    const int tid = threadIdx.x;

    // init: gumbel noise, exp(logits), rowsum; emit gumbel output
    for (int j = tid; j < NN; j += 1024) {
        float lg = logits[j];
        float u  = unif[j];
        float g  = lg + (-logf(-logf(u + EPSG) + EPSG));
        s_gum[j]   = g;
        s_logit[j] = lg;
        s_elog[j]  = expf(lg);
        s_row[j]   = rowsum0[j];
        out[NN + j] = g;           // gumbel_logits output
    }
    __syncthreads();

    for (int t = 0; t < NN; ++t) {
        // --- scan: masked argmax + sum of exp(logits) over zero-rowsum set ---
        float bv = -INFINITY;
        int   bi = NN;
        float ss = 0.f;
#pragma unroll
        for (int k = 0; k < 3; ++k) {
            int j = tid + k * 1024;
            bool z = (s_row[j] == 0.0f);
            float g = z ? s_gum[j] : -INFINITY;
            ss += z ? s_elog[j] : 0.f;
            if (g > bv) { bv = g; bi = j; }   // strict >: keeps lowest index on tie
        }
        // wave-level reduce (64 lanes)
#pragma unroll
        for (int off = 32; off > 0; off >>= 1) {
            float ov = __shfl_down(bv, off);
            int   oi = __shfl_down(bi, off);
            float os = __shfl_down(ss, off);
            ss += os;
            if (ov > bv || (ov == bv && oi < bi)) { bv = ov; bi = oi; }
        }
        if ((tid & 63) == 0) {
            int w = tid >> 6;
            red_val[w] = bv; red_idx[w] = bi; red_sum[w] = ss;
        }
        __syncthreads();
        // wave 0 reduces the 16 partials
        if (tid < 64) {
            bv = (tid < 16) ? red_val[tid] : -INFINITY;
            bi = (tid < 16) ? red_idx[tid] : NN;
            ss = (tid < 16) ? red_sum[tid] : 0.f;
#pragma unroll
            for (int off = 8; off > 0; off >>= 1) {
                float ov = __shfl_down(bv, off);
                int   oi = __shfl_down(bi, off);
                float os = __shfl_down(ss, off);
                ss += os;
                if (ov > bv || (ov == bv && oi < bi)) { bv = ov; bi = oi; }
            }
            if (tid == 0) {
                s_sel = bi;
                if (bi < NN) {
                    s_row[bi] = -1.0f;   // selected sentinel (never 0 again)
                    out[bi] = -logf(expf(-s_logit[bi]) * ss + 1e-10f);
                }
            }
        }
        __syncthreads();
        // --- update rowsums with packed column of selected node ---
        const int sel = s_sel;
        if (sel < NN && tid < NW) {
            unsigned bits = packedT[(size_t)sel * NW + tid];
            int base = tid * 32;
            while (bits) {
                int k = __ffs(bits) - 1;
                bits &= bits - 1u;
                s_row[base + k] -= 1.0f;
            }
        }
        __syncthreads();
    }
}

extern "C" void kernel_launch(void* const* d_in, const int* in_sizes, int n_in,
                              void* d_out, int out_size, void* d_ws, size_t ws_size,
                              hipStream_t stream) {
    const float* logits = (const float*)d_in[0];
    const float* adj    = (const float*)d_in[1];
    const float* unif   = (const float*)d_in[2];
    float* out = (float*)d_out;

    float*    rowsum  = (float*)d_ws;                       // 12 KB
    unsigned* packedT = (unsigned*)((char*)d_ws + 16384);   // 1.18 MB

    rowsum_kernel<<<NN, 256, 0, stream>>>(adj, rowsum);
    pack_kernel<<<dim3(NN / 256, NW), 256, 0, stream>>>(adj, packedT);
    topo_kernel<<<1, 1024, 0, stream>>>(logits, unif, rowsum, packedT, out);
}

// Round 2
// 3426.728 us; speedup vs baseline: 2.0110x; 2.0110x over previous
//
#include <hip/hip_runtime.h>
#include <math.h>

#define NN 3072
#define NW 96            // NN/32 packed words per column
#define EPSG 1e-20f

// ---------- prep 1: rowsum0[i] = sum_c adj[i][c] ----------
__global__ __launch_bounds__(256) void rowsum_kernel(const float* __restrict__ adj,
                                                     float* __restrict__ rowsum) {
    int row = blockIdx.x;
    const float* r = adj + (size_t)row * NN;
    float s = 0.f;
    for (int c = threadIdx.x; c < NN; c += 256) s += r[c];
#pragma unroll
    for (int off = 32; off > 0; off >>= 1) s += __shfl_down(s, off);
    __shared__ float ps[4];
    if ((threadIdx.x & 63) == 0) ps[threadIdx.x >> 6] = s;
    __syncthreads();
    if (threadIdx.x == 0) rowsum[row] = (ps[0] + ps[1]) + (ps[2] + ps[3]);
}

// ---------- prep 2: packedT[c][w] bit k = (adj[32w+k][c] != 0) ----------
__global__ __launch_bounds__(256) void pack_kernel(const float* __restrict__ adj,
                                                   unsigned* __restrict__ packedT) {
    int c = blockIdx.x * 256 + threadIdx.x;
    int w = blockIdx.y;
    const float* base = adj + (size_t)(w * 32) * NN + c;
    unsigned bits = 0u;
#pragma unroll
    for (int k = 0; k < 32; ++k)
        bits |= (base[(size_t)k * NN] != 0.0f) ? (1u << k) : 0u;
    packedT[(size_t)c * NW + w] = bits;
}

// ---------- prep 3: gumbel logits + derived per-node arrays ----------
__global__ __launch_bounds__(256) void gumbel_kernel(const float* __restrict__ logits,
                                                     const float* __restrict__ unif,
                                                     const float* __restrict__ rowsum,
                                                     float* __restrict__ out,
                                                     float* __restrict__ gum,
                                                     float* __restrict__ elog,
                                                     float* __restrict__ einv,
                                                     float* __restrict__ key0,
                                                     int* __restrict__ indeg) {
    int j = blockIdx.x * 256 + threadIdx.x;
    float lg = logits[j];
    float u  = unif[j];
    float g  = lg + (-logf(-logf(u + EPSG) + EPSG));
    out[NN + j] = g;                 // gumbel_logits output
    gum[j]  = g;
    elog[j] = expf(lg);
    einv[j] = expf(-lg);
    float rs = rowsum[j];
    key0[j] = (rs == 0.0f) ? g : -INFINITY;
    indeg[j] = (int)rs;
}

// monotonic order-preserving float->u32 map
__device__ __forceinline__ unsigned enc32(float v) {
    unsigned u = __float_as_uint(v);
    return (u & 0x80000000u) ? ~u : (u | 0x80000000u);
}

// ---------- sequential topo-sort: ONE wave, two-level tournament ----------
__global__ __launch_bounds__(64) void topo_kernel(const float* __restrict__ gum_g,
                                                  const float* __restrict__ elog_g,
                                                  const float* __restrict__ einv_g,
                                                  const float* __restrict__ key0_g,
                                                  const int* __restrict__ indeg_g,
                                                  const unsigned* __restrict__ packedT,
                                                  float* __restrict__ out) {
    __shared__ float s_key[NN];     // gumbel if eligible, -inf otherwise
    __shared__ float s_gum[NN];
    __shared__ float s_elog[NN];
    __shared__ float s_einv[NN];
    __shared__ int   s_indeg[NN];
    __shared__ unsigned long long s_gkey[64];   // per-group (enc(val)<<32 | ~idx)
    __shared__ float s_S;

    const int lane = threadIdx.x;

    // stage ws arrays into LDS (float4)
    for (int i = 0; i < 12; ++i) {
        int x = i * 64 + lane;
        ((float4*)s_key)[x]  = ((const float4*)key0_g)[x];
        ((float4*)s_gum)[x]  = ((const float4*)gum_g)[x];
        ((float4*)s_elog)[x] = ((const float4*)elog_g)[x];
        ((float4*)s_einv)[x] = ((const float4*)einv_g)[x];
        ((int4*)s_indeg)[x]  = ((const int4*)indeg_g)[x];
    }
    __syncthreads();

    // init: per-lane group scan (lane l owns group l = indices [48l, 48l+48))
    {
        int base = lane * 48;
        unsigned benc = 0u;
        int bj = base;
        float ss = 0.f;
        for (int i = 0; i < 48; ++i) {
            float v = s_key[base + i];
            if (v != -INFINITY) ss += s_elog[base + i];
            unsigned e = enc32(v);
            if (e > benc) { benc = e; bj = base + i; }
        }
        s_gkey[lane] = ((unsigned long long)benc << 32) | (unsigned long long)(unsigned)(~bj);
#pragma unroll
        for (int off = 1; off < 64; off <<= 1) ss += __shfl_xor(ss, off);
        if (lane == 0) s_S = ss;
    }
    __syncthreads();

    for (int t = 0; t < NN; ++t) {
        // --- top-level argmax over 64 group keys ---
        unsigned long long k64 = s_gkey[lane];
        unsigned vhi = (unsigned)(k64 >> 32);
        unsigned m = vhi;
#pragma unroll
        for (int off = 1; off < 64; off <<= 1) {
            unsigned o = __shfl_xor(m, off);
            m = (o > m) ? o : m;
        }
        unsigned long long ball = __ballot(vhi == m);
        int w = (int)__ffsll(ball) - 1;              // lowest group wins ties
        int sel = (int)(~__shfl((unsigned)k64, w));
        int g = sel / 48;

        // --- issue packed-column loads early (L2-resident) ---
        uint2 wb = make_uint2(0u, 0u);
        if (lane < 48) wb = *((const uint2*)(packedT + (size_t)sel * NW) + lane);

        // --- emit log_prob, update S, remove sel ---
        if (lane == 0) {
            float Snow = s_S;
            out[sel] = -logf(s_einv[sel] * Snow + 1e-10f);
            atomicAdd(&s_S, -s_elog[sel]);
            s_key[sel] = -INFINITY;
        }
        __syncthreads();

        // --- rescan group g (pre-insertion state); overlaps column-load latency ---
        float rv = (lane < 48) ? s_key[g * 48 + lane] : -INFINITY;
        unsigned re = enc32(rv);
        unsigned rm = re;
#pragma unroll
        for (int off = 1; off < 64; off <<= 1) {
            unsigned o = __shfl_xor(rm, off);
            rm = (o > rm) ? o : rm;
        }
        unsigned long long rball = __ballot(re == rm);
        int w0 = (int)__ffsll(rball) - 1;
        if (lane == 0)
            s_gkey[g] = ((unsigned long long)rm << 32)
                      | (unsigned long long)(unsigned)(~(g * 48 + w0));
        __syncthreads();

        // --- apply column of sel: decrement indegrees, insert newly-eligible ---
        if (lane < 48) {
#pragma unroll
            for (int h = 0; h < 2; ++h) {
                unsigned bits = h ? wb.y : wb.x;
                const int wbase = (lane * 2 + h) * 32;
                while (bits) {
                    int b = __ffs(bits) - 1;
                    bits &= bits - 1u;
                    int j2 = wbase + b;
                    int d = s_indeg[j2] - 1;         // each j2 unique to one lane
                    s_indeg[j2] = d;
                    if (d == 0) {
                        float gv = s_gum[j2];
                        s_key[j2] = gv;
                        atomicAdd(&s_S, s_elog[j2]);
                        atomicMax(&s_gkey[j2 / 48],
                                  ((unsigned long long)enc32(gv) << 32)
                                | (unsigned long long)(unsigned)(~j2));
                    }
                }
            }
        }
        __syncthreads();
    }
}

extern "C" void kernel_launch(void* const* d_in, const int* in_sizes, int n_in,
                              void* d_out, int out_size, void* d_ws, size_t ws_size,
                              hipStream_t stream) {
    const float* logits = (const float*)d_in[0];
    const float* adj    = (const float*)d_in[1];
    const float* unif   = (const float*)d_in[2];
    float* out = (float*)d_out;

    char* ws = (char*)d_ws;
    float*    rowsum  = (float*)(ws + 0);                 // 12 KB
    unsigned* packedT = (unsigned*)(ws + 16384);          // 1,179,648 B
    float*    gum     = (float*)(ws + 1196032);
    float*    elog    = (float*)(ws + 1208320);
    float*    einv    = (float*)(ws + 1220608);
    float*    key0    = (float*)(ws + 1232896);
    int*      indeg   = (int*)  (ws + 1245184);

    rowsum_kernel<<<NN, 256, 0, stream>>>(adj, rowsum);
    pack_kernel<<<dim3(NN / 256, NW), 256, 0, stream>>>(adj, packedT);
    gumbel_kernel<<<NN / 256, 256, 0, stream>>>(logits, unif, rowsum, out,
                                                gum, elog, einv, key0, indeg);
    topo_kernel<<<1, 64, 0, stream>>>(gum, elog, einv, key0, indeg, packedT, out);
}

// Round 3
// 2936.907 us; speedup vs baseline: 2.3464x; 1.1668x over previous
//
#include <hip/hip_runtime.h>
#include <math.h>

#define NN 3072
#define NW 96            // NN/32 packed words per column
#define EPSG 1e-20f

// ---------- prep 1: rowsum0[i] = sum_c adj[i][c] ----------
__global__ __launch_bounds__(256) void rowsum_kernel(const float* __restrict__ adj,
                                                     float* __restrict__ rowsum) {
    int row = blockIdx.x;
    const float* r = adj + (size_t)row * NN;
    float s = 0.f;
    for (int c = threadIdx.x; c < NN; c += 256) s += r[c];
#pragma unroll
    for (int off = 32; off > 0; off >>= 1) s += __shfl_down(s, off);
    __shared__ float ps[4];
    if ((threadIdx.x & 63) == 0) ps[threadIdx.x >> 6] = s;
    __syncthreads();
    if (threadIdx.x == 0) rowsum[row] = (ps[0] + ps[1]) + (ps[2] + ps[3]);
}

// ---------- prep 2: packedT[c][w] bit k = (adj[32w+k][c] != 0) ----------
__global__ __launch_bounds__(256) void pack_kernel(const float* __restrict__ adj,
                                                   unsigned* __restrict__ packedT) {
    int c = blockIdx.x * 256 + threadIdx.x;
    int w = blockIdx.y;
    const float* base = adj + (size_t)(w * 32) * NN + c;
    unsigned bits = 0u;
#pragma unroll
    for (int k = 0; k < 32; ++k)
        bits |= (base[(size_t)k * NN] != 0.0f) ? (1u << k) : 0u;
    packedT[(size_t)c * NW + w] = bits;
}

// ---------- prep 3: gumbel logits + derived per-node arrays ----------
__global__ __launch_bounds__(256) void gumbel_kernel(const float* __restrict__ logits,
                                                     const float* __restrict__ unif,
                                                     const float* __restrict__ rowsum,
                                                     float* __restrict__ out,
                                                     float* __restrict__ gum,
                                                     float* __restrict__ elog,
                                                     float* __restrict__ einv,
                                                     float* __restrict__ key0,
                                                     int* __restrict__ indeg) {
    int j = blockIdx.x * 256 + threadIdx.x;
    float lg = logits[j];
    float u  = unif[j];
    float g  = lg + (-logf(-logf(u + EPSG) + EPSG));
    out[NN + j] = g;                 // gumbel_logits output
    gum[j]  = g;
    elog[j] = expf(lg);
    einv[j] = expf(-lg);
    float rs = rowsum[j];
    key0[j] = (rs == 0.0f) ? g : -INFINITY;
    indeg[j] = (int)rs;
}

// monotonic order-preserving float->u32 map
__device__ __forceinline__ unsigned enc32(float v) {
    unsigned u = __float_as_uint(v);
    return (u & 0x80000000u) ? ~u : (u | 0x80000000u);
}

// DPP wave64 reduce: result valid in lane 63 (VALU-latency cross-lane, no LDS)
__device__ __forceinline__ unsigned wmax_u32(unsigned v) {
    unsigned t;
    t = (unsigned)__builtin_amdgcn_update_dpp(0, (int)v, 0x111, 0xf, 0xf, true); v = t > v ? t : v;
    t = (unsigned)__builtin_amdgcn_update_dpp(0, (int)v, 0x112, 0xf, 0xf, true); v = t > v ? t : v;
    t = (unsigned)__builtin_amdgcn_update_dpp(0, (int)v, 0x114, 0xf, 0xf, true); v = t > v ? t : v;
    t = (unsigned)__builtin_amdgcn_update_dpp(0, (int)v, 0x118, 0xf, 0xf, true); v = t > v ? t : v;
    t = (unsigned)__builtin_amdgcn_update_dpp(0, (int)v, 0x142, 0xf, 0xf, true); v = t > v ? t : v;
    t = (unsigned)__builtin_amdgcn_update_dpp(0, (int)v, 0x143, 0xf, 0xf, true); v = t > v ? t : v;
    return v;
}
__device__ __forceinline__ float wsum_f32(float v) {
    int t;
    t = __builtin_amdgcn_update_dpp(0, __float_as_int(v), 0x111, 0xf, 0xf, true); v += __int_as_float(t);
    t = __builtin_amdgcn_update_dpp(0, __float_as_int(v), 0x112, 0xf, 0xf, true); v += __int_as_float(t);
    t = __builtin_amdgcn_update_dpp(0, __float_as_int(v), 0x114, 0xf, 0xf, true); v += __int_as_float(t);
    t = __builtin_amdgcn_update_dpp(0, __float_as_int(v), 0x118, 0xf, 0xf, true); v += __int_as_float(t);
    t = __builtin_amdgcn_update_dpp(0, __float_as_int(v), 0x142, 0xf, 0xf, true); v += __int_as_float(t);
    t = __builtin_amdgcn_update_dpp(0, __float_as_int(v), 0x143, 0xf, 0xf, true); v += __int_as_float(t);
    return v;
}
__device__ __forceinline__ int rdlane(int v, int l) { return __builtin_amdgcn_readlane(v, l); }

// ---------- sequential topo-sort: ONE wave, register-resident tournament ----------
__global__ __launch_bounds__(64) void topo_kernel(const float* __restrict__ gum_g,
                                                  const float* __restrict__ elog_g,
                                                  const float* __restrict__ einv_g,
                                                  const float* __restrict__ key0_g,
                                                  const int* __restrict__ indeg_g,
                                                  const unsigned* __restrict__ packedT,
                                                  float* __restrict__ out) {
    __shared__ float s_key[NN];     // gumbel if eligible, -inf otherwise
    __shared__ float s_gum[NN];
    __shared__ float s_elog[NN];
    __shared__ float s_einv[NN];
    __shared__ int   s_indeg[NN];

    const int lane = threadIdx.x;

    // stage ws arrays into LDS (float4)
    for (int i = 0; i < 12; ++i) {
        int x = i * 64 + lane;
        ((float4*)s_key)[x]  = ((const float4*)key0_g)[x];
        ((float4*)s_gum)[x]  = ((const float4*)gum_g)[x];
        ((float4*)s_elog)[x] = ((const float4*)elog_g)[x];
        ((float4*)s_einv)[x] = ((const float4*)einv_g)[x];
        ((int4*)s_indeg)[x]  = ((const int4*)indeg_g)[x];
    }
    __syncthreads();

    // init: lane l owns group l = indices [48l, 48l+48); key in REGISTER
    unsigned long long mykey;
    float S;
    {
        int base = lane * 48;
        unsigned benc = 0u;
        int bj = base;
        float ssl = 0.f;
        for (int i = 0; i < 48; ++i) {
            float v = s_key[base + i];
            if (v != -INFINITY) ssl += s_elog[base + i];
            unsigned e = enc32(v);
            if (e > benc) { benc = e; bj = base + i; }
        }
        mykey = ((unsigned long long)benc << 32) | (unsigned long long)(unsigned)(~bj);
        float tot = wsum_f32(ssl);
        S = __int_as_float(rdlane(__float_as_int(tot), 63));
    }
    __syncthreads();

    for (int t = 0; t < NN; ++t) {
        // --- phase A: argmax over 64 register keys (pure VALU/SALU) ---
        unsigned vhi = (unsigned)(mykey >> 32);
        unsigned mx = (unsigned)rdlane((int)wmax_u32(vhi), 63);
        unsigned long long ball = __ballot(vhi == mx);
        int g = (int)__ffsll(ball) - 1;              // winner lane == winner group
        int sel = (int)(~(unsigned)rdlane((int)(unsigned)mykey, g));

        // --- phase B: issue packed-column loads (L2-resident, overlaps D) ---
        uint2 wb = make_uint2(0u, 0u);
        if (lane < 48) wb = ((const uint2*)(packedT + (size_t)sel * NW))[lane];

        // --- phase C: emit log_prob (S = pre-removal sum), start S update ---
        float elog_sel = s_elog[sel];                // same-address broadcast read
        float einv_sel = s_einv[sel];
        if (lane == 0) out[sel] = -logf(einv_sel * S + 1e-10f);
        S -= elog_sel;

        // --- phase D: rescan winner group (pre-insertion), update register key ---
        int rbase = g * 48;
        float rv = (lane < 48) ? s_key[rbase + lane] : -INFINITY;
        if (rbase + lane == sel) { rv = -INFINITY; s_key[sel] = -INFINITY; }
        unsigned re = enc32(rv);
        unsigned rmx = (unsigned)rdlane((int)wmax_u32(re), 63);
        unsigned long long rball = __ballot(re == rmx);
        int w0 = (int)__ffsll(rball) - 1;
        if (lane == g)
            mykey = ((unsigned long long)rmx << 32)
                  | (unsigned long long)(unsigned)(~(rbase + w0));

        // --- phase E: apply column; insertions via ballot-broadcast (registers) ---
        unsigned bits0 = wb.x, bits1 = wb.y;
        unsigned long long pend = 0ULL;
        float selog_add = 0.f;
        while (true) {
            if (pend == 0ULL) {
                while (bits0 | bits1) {
                    int h = bits0 ? 0 : 1;
                    unsigned bb = bits0 ? bits0 : bits1;
                    int b = __ffs(bb) - 1;
                    if (h) bits1 &= bits1 - 1u; else bits0 &= bits0 - 1u;
                    int j2 = lane * 64 + h * 32 + b;
                    int d = s_indeg[j2] - 1;         // j2 exclusive to this lane
                    s_indeg[j2] = d;
                    if (d == 0) {
                        float gv = s_gum[j2];
                        s_key[j2] = gv;
                        selog_add += s_elog[j2];
                        pend = ((unsigned long long)enc32(gv) << 32)
                             | (unsigned long long)(unsigned)(~j2);
                        break;
                    }
                }
            }
            unsigned long long anyb = __ballot(pend != 0ULL);
            if (anyb == 0ULL) break;
            int src = (int)__ffsll(anyb) - 1;
            unsigned khi = (unsigned)rdlane((int)(unsigned)(pend >> 32), src);
            unsigned klo = (unsigned)rdlane((int)(unsigned)pend, src);
            unsigned long long k = ((unsigned long long)khi << 32) | klo;
            int j3 = (int)(~klo);
            if (lane == j3 / 48 && k > mykey) mykey = k;
            if (lane == src) pend = 0ULL;
        }
        float add = wsum_f32(selog_add);
        S += __int_as_float(rdlane(__float_as_int(add), 63));

        __syncthreads();   // order s_key/s_indeg writes vs next-iter reads (1 wave: cheap)
    }
}

extern "C" void kernel_launch(void* const* d_in, const int* in_sizes, int n_in,
                              void* d_out, int out_size, void* d_ws, size_t ws_size,
                              hipStream_t stream) {
    const float* logits = (const float*)d_in[0];
    const float* adj    = (const float*)d_in[1];
    const float* unif   = (const float*)d_in[2];
    float* out = (float*)d_out;

    char* ws = (char*)d_ws;
    float*    rowsum  = (float*)(ws + 0);                 // 12 KB
    unsigned* packedT = (unsigned*)(ws + 16384);          // 1,179,648 B
    float*    gum     = (float*)(ws + 1196032);
    float*    elog    = (float*)(ws + 1208320);
    float*    einv    = (float*)(ws + 1220608);
    float*    key0    = (float*)(ws + 1232896);
    int*      indeg   = (int*)  (ws + 1245184);

    rowsum_kernel<<<NN, 256, 0, stream>>>(adj, rowsum);
    pack_kernel<<<dim3(NN / 256, NW), 256, 0, stream>>>(adj, packedT);
    gumbel_kernel<<<NN / 256, 256, 0, stream>>>(logits, unif, rowsum, out,
                                                gum, elog, einv, key0, indeg);
    topo_kernel<<<1, 64, 0, stream>>>(gum, elog, einv, key0, indeg, packedT, out);
}

// Round 4
// 2900.961 us; speedup vs baseline: 2.3755x; 1.0124x over previous
//
#include <hip/hip_runtime.h>
#include <math.h>

#define NN 3072
#define NW 96            // NN/32 packed words per column
#define EPSG 1e-20f

// ---------- prep 1: rowsum0[i] = sum_c adj[i][c] ----------
__global__ __launch_bounds__(256) void rowsum_kernel(const float* __restrict__ adj,
                                                     float* __restrict__ rowsum) {
    int row = blockIdx.x;
    const float* r = adj + (size_t)row * NN;
    float s = 0.f;
    for (int c = threadIdx.x; c < NN; c += 256) s += r[c];
#pragma unroll
    for (int off = 32; off > 0; off >>= 1) s += __shfl_down(s, off);
    __shared__ float ps[4];
    if ((threadIdx.x & 63) == 0) ps[threadIdx.x >> 6] = s;
    __syncthreads();
    if (threadIdx.x == 0) rowsum[row] = (ps[0] + ps[1]) + (ps[2] + ps[3]);
}

// ---------- prep 2: packedT[c][w] bit k = (adj[32w+k][c] != 0) ----------
__global__ __launch_bounds__(256) void pack_kernel(const float* __restrict__ adj,
                                                   unsigned* __restrict__ packedT) {
    int c = blockIdx.x * 256 + threadIdx.x;
    int w = blockIdx.y;
    const float* base = adj + (size_t)(w * 32) * NN + c;
    unsigned bits = 0u;
#pragma unroll
    for (int k = 0; k < 32; ++k)
        bits |= (base[(size_t)k * NN] != 0.0f) ? (1u << k) : 0u;
    packedT[(size_t)c * NW + w] = bits;
}

// ---------- prep 3: gumbel logits + derived per-node arrays ----------
__global__ __launch_bounds__(256) void gumbel_kernel(const float* __restrict__ logits,
                                                     const float* __restrict__ unif,
                                                     const float* __restrict__ rowsum,
                                                     float* __restrict__ out,
                                                     float* __restrict__ gum,
                                                     float* __restrict__ elog,
                                                     float* __restrict__ einv,
                                                     float* __restrict__ key0,
                                                     int* __restrict__ indeg) {
    int j = blockIdx.x * 256 + threadIdx.x;
    float lg = logits[j];
    float u  = unif[j];
    float g  = lg + (-logf(-logf(u + EPSG) + EPSG));
    out[NN + j] = g;                 // gumbel_logits output
    gum[j]  = g;
    elog[j] = expf(lg);
    einv[j] = expf(-lg);
    float rs = rowsum[j];
    key0[j] = (rs == 0.0f) ? g : -INFINITY;
    indeg[j] = (int)rs;
}

// monotonic order-preserving float->u32 map
__device__ __forceinline__ unsigned enc32(float v) {
    unsigned u = __float_as_uint(v);
    return (u & 0x80000000u) ? ~u : (u | 0x80000000u);
}

// DPP wave64 reduce: result valid in lane 63 (VALU-latency cross-lane, no LDS)
__device__ __forceinline__ unsigned wmax_u32(unsigned v) {
    unsigned t;
    t = (unsigned)__builtin_amdgcn_update_dpp(0, (int)v, 0x111, 0xf, 0xf, true); v = t > v ? t : v;
    t = (unsigned)__builtin_amdgcn_update_dpp(0, (int)v, 0x112, 0xf, 0xf, true); v = t > v ? t : v;
    t = (unsigned)__builtin_amdgcn_update_dpp(0, (int)v, 0x114, 0xf, 0xf, true); v = t > v ? t : v;
    t = (unsigned)__builtin_amdgcn_update_dpp(0, (int)v, 0x118, 0xf, 0xf, true); v = t > v ? t : v;
    t = (unsigned)__builtin_amdgcn_update_dpp(0, (int)v, 0x142, 0xf, 0xf, true); v = t > v ? t : v;
    t = (unsigned)__builtin_amdgcn_update_dpp(0, (int)v, 0x143, 0xf, 0xf, true); v = t > v ? t : v;
    return v;
}
__device__ __forceinline__ float wsum_f32(float v) {
    int t;
    t = __builtin_amdgcn_update_dpp(0, __float_as_int(v), 0x111, 0xf, 0xf, true); v += __int_as_float(t);
    t = __builtin_amdgcn_update_dpp(0, __float_as_int(v), 0x112, 0xf, 0xf, true); v += __int_as_float(t);
    t = __builtin_amdgcn_update_dpp(0, __float_as_int(v), 0x114, 0xf, 0xf, true); v += __int_as_float(t);
    t = __builtin_amdgcn_update_dpp(0, __float_as_int(v), 0x118, 0xf, 0xf, true); v += __int_as_float(t);
    t = __builtin_amdgcn_update_dpp(0, __float_as_int(v), 0x142, 0xf, 0xf, true); v += __int_as_float(t);
    t = __builtin_amdgcn_update_dpp(0, __float_as_int(v), 0x143, 0xf, 0xf, true); v += __int_as_float(t);
    return v;
}
__device__ __forceinline__ int rdlane(int v, int l) { return __builtin_amdgcn_readlane(v, l); }

// ---------- sequential topo-sort: wave 0 runs the loop; waves 1-3 warm L2 ----------
__global__ __launch_bounds__(256) void topo_kernel(const float* __restrict__ gum_g,
                                                   const float* __restrict__ elog_g,
                                                   const float* __restrict__ einv_g,
                                                   const float* __restrict__ key0_g,
                                                   const int* __restrict__ indeg_g,
                                                   const unsigned* __restrict__ packedT,
                                                   float* __restrict__ out) {
    __shared__ float s_key[NN];     // gumbel if eligible, -inf otherwise
    __shared__ float s_gum[NN];
    __shared__ float s_elog[NN];
    __shared__ float s_einv[NN];
    __shared__ int   s_indeg[NN];

    const int tid = threadIdx.x;

    if (tid >= 64) {
        // waves 1-3: stream packedT through this CU's L1/L2 (same XCD as wave 0),
        // so the sequential loop's column reads become local-L2 hits.
        const uint4* p = (const uint4*)packedT;
        unsigned acc = 0u;
        for (int i = tid - 64; i < NN * NW / 4; i += 192) {
            uint4 v = p[i];
            acc ^= v.x ^ v.y ^ v.z ^ v.w;
        }
        asm volatile("" :: "v"(acc));   // keep loads live
        return;
    }

    const int lane = tid;

    // stage per-node arrays into LDS (float4); single wave: in-order LDS, no barrier
    for (int i = 0; i < 12; ++i) {
        int x = i * 64 + lane;
        ((float4*)s_key)[x]  = ((const float4*)key0_g)[x];
        ((float4*)s_gum)[x]  = ((const float4*)gum_g)[x];
        ((float4*)s_elog)[x] = ((const float4*)elog_g)[x];
        ((float4*)s_einv)[x] = ((const float4*)einv_g)[x];
        ((int4*)s_indeg)[x]  = ((const int4*)indeg_g)[x];
    }

    // init: lane l owns group l = indices [48l, 48l+48); key in REGISTER
    unsigned long long mykey;
    float S;
    {
        int base = lane * 48;
        unsigned benc = 0u;
        int bj = base;
        float ssl = 0.f;
        for (int i = 0; i < 48; ++i) {
            float v = s_key[base + i];
            if (v != -INFINITY) ssl += s_elog[base + i];
            unsigned e = enc32(v);
            if (e > benc) { benc = e; bj = base + i; }
        }
        mykey = ((unsigned long long)benc << 32) | (unsigned long long)(unsigned)(~bj);
        float tot = wsum_f32(ssl);
        S = __int_as_float(rdlane(__float_as_int(tot), 63));
    }

    for (int t = 0; t < NN; ++t) {
        // --- phase A: argmax over 64 register keys (pure VALU/SALU) ---
        unsigned vhi = (unsigned)(mykey >> 32);
        unsigned mx = (unsigned)rdlane((int)wmax_u32(vhi), 63);
        unsigned long long ball = __ballot(vhi == mx);
        int g = (int)__ffsll(ball) - 1;              // winner lane == winner group
        int sel = (int)(~(unsigned)rdlane((int)(unsigned)mykey, g));

        // --- phase B: issue packed-column loads (local L2 after warmup) ---
        uint2 wb = make_uint2(0u, 0u);
        if (lane < 48) wb = ((const uint2*)(packedT + (size_t)sel * NW))[lane];

        // --- phase C: emit log_prob (S = pre-removal sum); store is fire-and-forget ---
        float elog_sel = s_elog[sel];                // same-address broadcast read
        float einv_sel = s_einv[sel];
        if (lane == 0) out[sel] = -logf(einv_sel * S + 1e-10f);
        S -= elog_sel;

        // --- phase D: rescan winner group (pre-insertion), update register key ---
        int rbase = g * 48;
        float rv = (lane < 48) ? s_key[rbase + lane] : -INFINITY;
        if (rbase + lane == sel) { rv = -INFINITY; s_key[sel] = -INFINITY; }
        unsigned re = enc32(rv);
        unsigned rmx = (unsigned)rdlane((int)wmax_u32(re), 63);
        unsigned long long rball = __ballot(re == rmx);
        int w0 = (int)__ffsll(rball) - 1;
        if (lane == g)
            mykey = ((unsigned long long)rmx << 32)
                  | (unsigned long long)(unsigned)(~(rbase + w0));

        // --- phase E: apply column; insertions via ballot-broadcast (registers) ---
        unsigned bits0 = wb.x, bits1 = wb.y;
        unsigned long long pend = 0ULL;
        float selog_add = 0.f;
        while (true) {
            if (pend == 0ULL) {
                while (bits0 | bits1) {
                    int h = bits0 ? 0 : 1;
                    unsigned bb = bits0 ? bits0 : bits1;
                    int b = __ffs(bb) - 1;
                    if (h) bits1 &= bits1 - 1u; else bits0 &= bits0 - 1u;
                    int j2 = lane * 64 + h * 32 + b;
                    int d = s_indeg[j2] - 1;         // j2 exclusive to this lane
                    s_indeg[j2] = d;
                    if (d == 0) {
                        float gv = s_gum[j2];
                        s_key[j2] = gv;
                        selog_add += s_elog[j2];
                        pend = ((unsigned long long)enc32(gv) << 32)
                             | (unsigned long long)(unsigned)(~j2);
                        break;
                    }
                }
            }
            unsigned long long anyb = __ballot(pend != 0ULL);
            if (anyb == 0ULL) break;
            int src = (int)__ffsll(anyb) - 1;
            unsigned khi = (unsigned)rdlane((int)(unsigned)(pend >> 32), src);
            unsigned klo = (unsigned)rdlane((int)(unsigned)pend, src);
            unsigned long long k = ((unsigned long long)khi << 32) | klo;
            int j3 = (int)(~klo);
            if (lane == j3 / 48 && k > mykey) mykey = k;
            if (lane == src) pend = 0ULL;
        }
        float add = wsum_f32(selog_add);
        S += __int_as_float(rdlane(__float_as_int(add), 63));
        // no barrier: single wave, LDS ops complete in program order
    }
}

extern "C" void kernel_launch(void* const* d_in, const int* in_sizes, int n_in,
                              void* d_out, int out_size, void* d_ws, size_t ws_size,
                              hipStream_t stream) {
    const float* logits = (const float*)d_in[0];
    const float* adj    = (const float*)d_in[1];
    const float* unif   = (const float*)d_in[2];
    float* out = (float*)d_out;

    char* ws = (char*)d_ws;
    float*    rowsum  = (float*)(ws + 0);                 // 12 KB
    unsigned* packedT = (unsigned*)(ws + 16384);          // 1,179,648 B
    float*    gum     = (float*)(ws + 1196032);
    float*    elog    = (float*)(ws + 1208320);
    float*    einv    = (float*)(ws + 1220608);
    float*    key0    = (float*)(ws + 1232896);
    int*      indeg   = (int*)  (ws + 1245184);

    rowsum_kernel<<<NN, 256, 0, stream>>>(adj, rowsum);
    pack_kernel<<<dim3(NN / 256, NW), 256, 0, stream>>>(adj, packedT);
    gumbel_kernel<<<NN / 256, 256, 0, stream>>>(logits, unif, rowsum, out,
                                                gum, elog, einv, key0, indeg);
    topo_kernel<<<1, 256, 0, stream>>>(gum, elog, einv, key0, indeg, packedT, out);
}

// Round 5
// 2664.758 us; speedup vs baseline: 2.5861x; 1.0886x over previous
//
#include <hip/hip_runtime.h>
#include <math.h>

#define NN 3072
#define NW 96            // NN/32 packed words per column
#define EPSG 1e-20f
typedef unsigned long long u64;

// ---------- prep 1: rowsum0[i] = sum_c adj[i][c] ----------
__global__ __launch_bounds__(256) void rowsum_kernel(const float* __restrict__ adj,
                                                     float* __restrict__ rowsum) {
    int row = blockIdx.x;
    const float* r = adj + (size_t)row * NN;
    float s = 0.f;
    for (int c = threadIdx.x; c < NN; c += 256) s += r[c];
#pragma unroll
    for (int off = 32; off > 0; off >>= 1) s += __shfl_down(s, off);
    __shared__ float ps[4];
    if ((threadIdx.x & 63) == 0) ps[threadIdx.x >> 6] = s;
    __syncthreads();
    if (threadIdx.x == 0) rowsum[row] = (ps[0] + ps[1]) + (ps[2] + ps[3]);
}

// ---------- prep 2: packedT[c][w] bit k = (adj[32w+k][c] != 0) ----------
__global__ __launch_bounds__(256) void pack_kernel(const float* __restrict__ adj,
                                                   unsigned* __restrict__ packedT) {
    int c = blockIdx.x * 256 + threadIdx.x;
    int w = blockIdx.y;
    const float* base = adj + (size_t)(w * 32) * NN + c;
    unsigned bits = 0u;
#pragma unroll
    for (int k = 0; k < 32; ++k)
        bits |= (base[(size_t)k * NN] != 0.0f) ? (1u << k) : 0u;
    packedT[(size_t)c * NW + w] = bits;
}

// monotonic order-preserving float->u32 map
__device__ __forceinline__ unsigned enc32(float v) {
    unsigned u = __float_as_uint(v);
    return (u & 0x80000000u) ? ~u : (u | 0x80000000u);
}

// ---------- prep 3: gumbel + derived per-node arrays ----------
__global__ __launch_bounds__(256) void gumbel_kernel(const float* __restrict__ logits,
                                                     const float* __restrict__ unif,
                                                     const float* __restrict__ rowsum,
                                                     float* __restrict__ out,
                                                     float* __restrict__ elog,
                                                     float* __restrict__ einv,
                                                     unsigned* __restrict__ keyenc,
                                                     int* __restrict__ indeg) {
    int j = blockIdx.x * 256 + threadIdx.x;
    float lg = logits[j];
    float u  = unif[j];
    float g  = lg + (-logf(-logf(u + EPSG) + EPSG));
    out[NN + j] = g;                 // gumbel_logits output
    elog[j] = expf(lg);
    einv[j] = expf(-lg);
    keyenc[j] = enc32(g);
    indeg[j] = (int)rowsum[j];
}

// DPP wave64 max-reduce: result valid in lane 63
__device__ __forceinline__ unsigned wmax_u32(unsigned v) {
    unsigned t;
    t = (unsigned)__builtin_amdgcn_update_dpp(0, (int)v, 0x111, 0xf, 0xf, true); v = t > v ? t : v;
    t = (unsigned)__builtin_amdgcn_update_dpp(0, (int)v, 0x112, 0xf, 0xf, true); v = t > v ? t : v;
    t = (unsigned)__builtin_amdgcn_update_dpp(0, (int)v, 0x114, 0xf, 0xf, true); v = t > v ? t : v;
    t = (unsigned)__builtin_amdgcn_update_dpp(0, (int)v, 0x118, 0xf, 0xf, true); v = t > v ? t : v;
    t = (unsigned)__builtin_amdgcn_update_dpp(0, (int)v, 0x142, 0xf, 0xf, true); v = t > v ? t : v;
    t = (unsigned)__builtin_amdgcn_update_dpp(0, (int)v, 0x143, 0xf, 0xf, true); v = t > v ? t : v;
    return v;
}
__device__ __forceinline__ float wsum_f32(float v) {
    int t;
    t = __builtin_amdgcn_update_dpp(0, __float_as_int(v), 0x111, 0xf, 0xf, true); v += __int_as_float(t);
    t = __builtin_amdgcn_update_dpp(0, __float_as_int(v), 0x112, 0xf, 0xf, true); v += __int_as_float(t);
    t = __builtin_amdgcn_update_dpp(0, __float_as_int(v), 0x114, 0xf, 0xf, true); v += __int_as_float(t);
    t = __builtin_amdgcn_update_dpp(0, __float_as_int(v), 0x118, 0xf, 0xf, true); v += __int_as_float(t);
    t = __builtin_amdgcn_update_dpp(0, __float_as_int(v), 0x142, 0xf, 0xf, true); v += __int_as_float(t);
    t = __builtin_amdgcn_update_dpp(0, __float_as_int(v), 0x143, 0xf, 0xf, true); v += __int_as_float(t);
    return v;
}
__device__ __forceinline__ int rdlane(int v, int l) { return __builtin_amdgcn_readlane(v, l); }
__device__ __forceinline__ int div48(int j) { return ((j >> 4) * 21846) >> 16; }  // exact for j<3072

// ---------- sequential topo-sort: wave 0 loops; waves 1-3 warm L2 ----------
__global__ __launch_bounds__(256) void topo_kernel(const float* __restrict__ elog_g,
                                                   const float* __restrict__ einv_g,
                                                   const unsigned* __restrict__ keyenc_g,
                                                   const int* __restrict__ indeg_g,
                                                   const unsigned* __restrict__ packedT,
                                                   float* __restrict__ out) {
    __shared__ u64      s_node[NN];   // hi = indeg (0xFFFFFFFF once selected), lo = keyenc
    __shared__ float    s_elog[NN];
    __shared__ float    s_einv[NN];
    __shared__ float    s_slog[NN];   // S at each step
    __shared__ unsigned s_ssel[NN];   // sel at each step

    const int tid = threadIdx.x;

    if (tid >= 64) {
        // waves 1-3: pull packedT into this CU/XCD's caches
        const uint4* p = (const uint4*)packedT;
        unsigned acc = 0u;
        for (int i = tid - 64; i < NN * NW / 4; i += 192) {
            uint4 v = p[i];
            acc ^= v.x ^ v.y ^ v.z ^ v.w;
        }
        asm volatile("" :: "v"(acc));
        return;
    }
    const int lane = tid;

    // ---- stage: compose node words, copy elog/einv (vectorized) ----
    for (int i = 0; i < 12; ++i) {
        int x = i * 64 + lane;
        uint4 ke = ((const uint4*)keyenc_g)[x];
        uint4 dg = ((const uint4*)indeg_g)[x];
        s_node[4 * x + 0] = ((u64)dg.x << 32) | ke.x;
        s_node[4 * x + 1] = ((u64)dg.y << 32) | ke.y;
        s_node[4 * x + 2] = ((u64)dg.z << 32) | ke.z;
        s_node[4 * x + 3] = ((u64)dg.w << 32) | ke.w;
        ((float4*)s_elog)[x] = ((const float4*)elog_g)[x];
        ((float4*)s_einv)[x] = ((const float4*)einv_g)[x];
    }

    // ---- init: lane l owns group l = [48l, 48l+48); key in register ----
    u64 mykey;
    float S;
    {
        int base = lane * 48;
        unsigned benc = 0u;
        int bj = base;
        float ssl = 0.f;
        for (int i = 0; i < 48; ++i) {
            u64 nw = s_node[base + i];
            if ((unsigned)(nw >> 32) == 0u) {
                ssl += s_elog[base + i];
                unsigned e = (unsigned)nw;
                if (e > benc) { benc = e; bj = base + i; }
            }
        }
        mykey = ((u64)benc << 32) | (unsigned)(~bj);
        float tot = wsum_f32(ssl);
        S = __int_as_float(rdlane(__float_as_int(tot), 63));
    }

    // ---- initial tournament + initial prefetch ----
    u64 k;
    {
        unsigned vhi = (unsigned)(mykey >> 32);
        unsigned mx = (unsigned)rdlane((int)wmax_u32(vhi), 63);
        u64 ball = __ballot(vhi == mx);
        int gw = (int)__ffsll(ball) - 1;              // lowest group = lowest index
        unsigned lo = (unsigned)rdlane((int)(unsigned)mykey, gw);
        k = ((u64)mx << 32) | lo;
    }
    uint2 wb = make_uint2(0u, 0u);
    {
        unsigned sel0 = ~(unsigned)k;
        if (lane < 48) wb = ((const uint2*)(packedT + (size_t)sel0 * NW))[lane];
    }

    for (int t = 0; t < NN; ++t) {
        const unsigned sel = ~(unsigned)k;       // uniform
        const int g = div48((int)sel);

        // record (sel, S) pre-removal; mark sel ineligible
        if (lane == 0) {
            s_slog[t] = S;
            s_ssel[t] = sel;
            ((unsigned*)&s_node[sel])[1] = 0xFFFFFFFFu;
        }
        S -= s_elog[sel];                        // uniform broadcast read (off-chain)

        // D: rescan winner group (excluding sel) -> update mykey[g]
        {
            u64 nw = (lane < 48) ? s_node[g * 48 + lane] : 0ULL;
            bool elig = ((unsigned)(nw >> 32) == 0u) && (g * 48 + lane != (int)sel);
            unsigned re = elig ? (unsigned)nw : 0u;
            unsigned rmx = (unsigned)rdlane((int)wmax_u32(re), 63);
            u64 rball = __ballot(re == rmx);
            int w0 = (int)__ffsll(rball) - 1;
            if (lane == g)
                mykey = ((u64)rmx << 32) | (unsigned)(~(g * 48 + w0));
        }

        // E: apply prefetched column; insertions update mykey registers + S
        {
            unsigned bits0 = (lane < 48) ? wb.x : 0u;
            unsigned bits1 = (lane < 48) ? wb.y : 0u;
            u64 pend = 0ULL;
            while (true) {
                if (pend == 0ULL) {
                    while (bits0 | bits1) {
                        int h = bits0 ? 0 : 1;
                        unsigned bb = bits0 ? bits0 : bits1;
                        int b = __ffs(bb) - 1;
                        if (h) bits1 &= bits1 - 1u; else bits0 &= bits0 - 1u;
                        int j2 = lane * 64 + h * 32 + b;
                        u64 nw2 = s_node[j2];                 // one b64 read
                        unsigned hi = (unsigned)(nw2 >> 32);
                        ((unsigned*)&s_node[j2])[1] = hi - 1; // write hi word
                        if (hi == 1u) {                       // became eligible
                            pend = ((nw2 & 0xFFFFFFFFULL) << 32) | (unsigned)(~j2);
                            break;
                        }
                    }
                }
                u64 ab = __ballot(pend != 0ULL);
                if (ab == 0ULL) break;
                int src = (int)__ffsll(ab) - 1;
                unsigned klo = (unsigned)rdlane((int)(unsigned)pend, src);
                unsigned khi = (unsigned)rdlane((int)(unsigned)(pend >> 32), src);
                u64 kin = ((u64)khi << 32) | klo;
                int j3 = (int)~klo;
                int gj = div48(j3);
                if (lane == gj && kin > mykey) mykey = kin;
                S += s_elog[j3];                              // uniform broadcast read
                if (lane == src) pend = 0ULL;
            }
        }

        // A': tournament over mykeys (includes rescan + insertions) -> exact next winner
        {
            unsigned vhi = (unsigned)(mykey >> 32);
            unsigned mx = (unsigned)rdlane((int)wmax_u32(vhi), 63);
            u64 ball = __ballot(vhi == mx);
            int gw = (int)__ffsll(ball) - 1;
            unsigned lo = (unsigned)rdlane((int)(unsigned)mykey, gw);
            k = ((u64)mx << 32) | lo;
        }
        // prefetch next winner's column (consumed next iteration)
        {
            unsigned nsel = ~(unsigned)k;
            if (lane < 48) wb = ((const uint2*)(packedT + (size_t)nsel * NW))[lane];
        }
    }

    // ---- epilogue: all log_probs in parallel ----
    for (int i = lane; i < NN; i += 64) {
        unsigned si = s_ssel[i];
        float Si = s_slog[i];
        out[si] = -logf(s_einv[si] * Si + 1e-10f);
    }
}

extern "C" void kernel_launch(void* const* d_in, const int* in_sizes, int n_in,
                              void* d_out, int out_size, void* d_ws, size_t ws_size,
                              hipStream_t stream) {
    const float* logits = (const float*)d_in[0];
    const float* adj    = (const float*)d_in[1];
    const float* unif   = (const float*)d_in[2];
    float* out = (float*)d_out;

    char* ws = (char*)d_ws;
    float*    rowsum  = (float*)(ws + 0);                 // 12 KB
    unsigned* packedT = (unsigned*)(ws + 16384);          // 1,179,648 B
    float*    elog    = (float*)(ws + 1196032);
    float*    einv    = (float*)(ws + 1208320);
    unsigned* keyenc  = (unsigned*)(ws + 1220608);
    int*      indeg   = (int*)  (ws + 1232896);

    rowsum_kernel<<<NN, 256, 0, stream>>>(adj, rowsum);
    pack_kernel<<<dim3(NN / 256, NW), 256, 0, stream>>>(adj, packedT);
    gumbel_kernel<<<NN / 256, 256, 0, stream>>>(logits, unif, rowsum, out,
                                                elog, einv, keyenc, indeg);
    topo_kernel<<<1, 256, 0, stream>>>(elog, einv, keyenc, indeg, packedT, out);
}

// Round 6
// 1811.585 us; speedup vs baseline: 3.8040x; 1.4710x over previous
//
#include <hip/hip_runtime.h>
#include <math.h>

#define NN 3072
#define NW 96            // NN/32 packed words per column
#define EPSG 1e-20f
typedef unsigned long long u64;

// ---------- prep 1: rowsum0[i] = sum_c adj[i][c] ----------
__global__ __launch_bounds__(256) void rowsum_kernel(const float* __restrict__ adj,
                                                     float* __restrict__ rowsum) {
    int row = blockIdx.x;
    const float* r = adj + (size_t)row * NN;
    float s = 0.f;
    for (int c = threadIdx.x; c < NN; c += 256) s += r[c];
#pragma unroll
    for (int off = 32; off > 0; off >>= 1) s += __shfl_down(s, off);
    __shared__ float ps[4];
    if ((threadIdx.x & 63) == 0) ps[threadIdx.x >> 6] = s;
    __syncthreads();
    if (threadIdx.x == 0) rowsum[row] = (ps[0] + ps[1]) + (ps[2] + ps[3]);
}

// ---------- prep 2: packedT[c][w] bit k = (adj[32w+k][c] != 0) ----------
__global__ __launch_bounds__(256) void pack_kernel(const float* __restrict__ adj,
                                                   unsigned* __restrict__ packedT) {
    int c = blockIdx.x * 256 + threadIdx.x;
    int w = blockIdx.y;
    const float* base = adj + (size_t)(w * 32) * NN + c;
    unsigned bits = 0u;
#pragma unroll
    for (int k = 0; k < 32; ++k)
        bits |= (base[(size_t)k * NN] != 0.0f) ? (1u << k) : 0u;
    packedT[(size_t)c * NW + w] = bits;
}

// ---------- prep 2b: per-lane windows: packedT64[c*64+l] = bits [48l,48l+48) of col c ----------
__global__ __launch_bounds__(256) void repack_kernel(const unsigned* __restrict__ packedT,
                                                     u64* __restrict__ packedT64) {
    int x = blockIdx.x * 256 + threadIdx.x;   // x = c*64 + l
    int c = x >> 6, l = x & 63;
    int k = (3 * l) >> 1;                     // 48l = 32k + sh
    int sh = (l & 1) * 16;
    const unsigned* base = packedT + (size_t)c * NW + k;
    u64 w = ((u64)base[1] << 32) | base[0];
    packedT64[x] = (w >> sh) & 0xFFFFFFFFFFFFULL;
}

// monotonic order-preserving float->u32 map
__device__ __forceinline__ unsigned enc32(float v) {
    unsigned u = __float_as_uint(v);
    return (u & 0x80000000u) ? ~u : (u | 0x80000000u);
}

// ---------- prep 3: gumbel + derived per-node arrays ----------
__global__ __launch_bounds__(256) void gumbel_kernel(const float* __restrict__ logits,
                                                     const float* __restrict__ unif,
                                                     const float* __restrict__ rowsum,
                                                     float* __restrict__ out,
                                                     float* __restrict__ elog,
                                                     unsigned* __restrict__ keyenc,
                                                     int* __restrict__ indeg) {
    int j = blockIdx.x * 256 + threadIdx.x;
    float lg = logits[j];
    float u  = unif[j];
    float g  = lg + (-logf(-logf(u + EPSG) + EPSG));
    out[NN + j] = g;                 // gumbel_logits output
    elog[j] = expf(lg);
    keyenc[j] = enc32(g);
    indeg[j] = (int)rowsum[j];
}

// DPP wave64 max-reduce: result valid in lane 63
__device__ __forceinline__ unsigned wmax_u32(unsigned v) {
    unsigned t;
    t = (unsigned)__builtin_amdgcn_update_dpp(0, (int)v, 0x111, 0xf, 0xf, true); v = t > v ? t : v;
    t = (unsigned)__builtin_amdgcn_update_dpp(0, (int)v, 0x112, 0xf, 0xf, true); v = t > v ? t : v;
    t = (unsigned)__builtin_amdgcn_update_dpp(0, (int)v, 0x114, 0xf, 0xf, true); v = t > v ? t : v;
    t = (unsigned)__builtin_amdgcn_update_dpp(0, (int)v, 0x118, 0xf, 0xf, true); v = t > v ? t : v;
    t = (unsigned)__builtin_amdgcn_update_dpp(0, (int)v, 0x142, 0xf, 0xf, true); v = t > v ? t : v;
    t = (unsigned)__builtin_amdgcn_update_dpp(0, (int)v, 0x143, 0xf, 0xf, true); v = t > v ? t : v;
    return v;
}
__device__ __forceinline__ float wsum_f32(float v) {
    int t;
    t = __builtin_amdgcn_update_dpp(0, __float_as_int(v), 0x111, 0xf, 0xf, true); v += __int_as_float(t);
    t = __builtin_amdgcn_update_dpp(0, __float_as_int(v), 0x112, 0xf, 0xf, true); v += __int_as_float(t);
    t = __builtin_amdgcn_update_dpp(0, __float_as_int(v), 0x114, 0xf, 0xf, true); v += __int_as_float(t);
    t = __builtin_amdgcn_update_dpp(0, __float_as_int(v), 0x118, 0xf, 0xf, true); v += __int_as_float(t);
    t = __builtin_amdgcn_update_dpp(0, __float_as_int(v), 0x142, 0xf, 0xf, true); v += __int_as_float(t);
    t = __builtin_amdgcn_update_dpp(0, __float_as_int(v), 0x143, 0xf, 0xf, true); v += __int_as_float(t);
    return v;
}
__device__ __forceinline__ int rdlane(int v, int l) { return __builtin_amdgcn_readlane(v, l); }

// ---------- sequential topo-sort: wave 0 loops; waves 1-3 warm L2 ----------
__global__ __launch_bounds__(256) void topo_kernel(const float* __restrict__ elog_g,
                                                   const unsigned* __restrict__ keyenc_g,
                                                   const int* __restrict__ indeg_g,
                                                   const u64* __restrict__ packedT64,
                                                   float* __restrict__ out) {
    __shared__ u64      s_node[NN + 4]; // hi=indeg (0xFFFFFFFF once selected), lo=keyenc; +dummies
    __shared__ float    s_elog[NN];
    __shared__ float    s_slog[NN];
    __shared__ unsigned s_ssel[NN];

    const int tid = threadIdx.x;

    if (tid >= 64) {
        // waves 1-3: pull packedT64 into this CU/XCD's caches
        const uint4* p = (const uint4*)packedT64;
        unsigned acc = 0u;
        for (int i = tid - 64; i < NN * 64 * 8 / 16; i += 192) {
            uint4 v = p[i];
            acc ^= v.x ^ v.y ^ v.z ^ v.w;
        }
        asm volatile("" :: "v"(acc));
        return;
    }
    const int lane = tid;

    // ---- stage ----
    for (int i = 0; i < 12; ++i) {
        int x = i * 64 + lane;
        uint4 ke = ((const uint4*)keyenc_g)[x];
        uint4 dg = ((const uint4*)indeg_g)[x];
        s_node[4 * x + 0] = ((u64)dg.x << 32) | ke.x;
        s_node[4 * x + 1] = ((u64)dg.y << 32) | ke.y;
        s_node[4 * x + 2] = ((u64)dg.z << 32) | ke.z;
        s_node[4 * x + 3] = ((u64)dg.w << 32) | ke.w;
        ((float4*)s_elog)[x] = ((const float4*)elog_g)[x];
    }

    // ---- init: lane l owns group l = [48l, 48l+48) ----
    u64 mykey;
    float S;
    {
        int base = lane * 48;
        unsigned benc = 0u;
        int bj = base;
        float ssl = 0.f;
        for (int i = 0; i < 48; ++i) {
            u64 nw = s_node[base + i];
            if ((unsigned)(nw >> 32) == 0u) {
                ssl += s_elog[base + i];
                unsigned e = (unsigned)nw;
                if (e > benc) { benc = e; bj = base + i; }
            }
        }
        mykey = ((u64)benc << 32) | (unsigned)(~bj);
        float tot = wsum_f32(ssl);
        S = __int_as_float(rdlane(__float_as_int(tot), 63));
    }

    // ---- initial tournament + prefetch ----
    u64 k;
    {
        unsigned vhi = (unsigned)(mykey >> 32);
        unsigned mx = (unsigned)rdlane((int)wmax_u32(vhi), 63);
        u64 ball = __ballot(vhi == mx);
        int gw = (int)__ffsll(ball) - 1;
        unsigned lo = (unsigned)rdlane((int)(unsigned)mykey, gw);
        k = ((u64)mx << 32) | lo;
    }
    u64 wb = packedT64[(size_t)(~(unsigned)k) * 64 + lane];

    for (int t = 0; t < NN; ++t) {
        const int sel = (int)~(unsigned)k;      // uniform
        const int g = sel / 48;

        // record (off critical path) + marker
        if (lane == 0) {
            s_slog[t] = S;
            s_ssel[t] = (unsigned)sel;
            ((unsigned*)&s_node[sel])[1] = 0xFFFFFFFFu;
        }
        float elog_sel = s_elog[sel];           // uniform broadcast read (issue early)

        // ---- D: rescan winner group (read issued first) ----
        u64 nw = (lane < 48) ? s_node[g * 48 + lane] : 0ULL;
        bool elig = (lane < 48) && ((unsigned)(nw >> 32) == 0u) && (g * 48 + lane != sel);
        unsigned re = elig ? (unsigned)nw : 0u;
        unsigned rmx = (unsigned)rdlane((int)wmax_u32(re), 63);
        u64 rball = __ballot(re == rmx);
        int w0 = (int)__ffsll(rball) - 1;
        if (lane == g)
            mykey = ((u64)rmx << 32) | (unsigned)(~(g * 48 + w0));

        // ---- E: straight-line apply of my 48-bit window (<=2 bits fast path) ----
        u64 b = wb;
        int p0 = (int)__ffsll(b) - 1; bool h0 = (b != 0ULL); b &= b - 1;
        int p1 = (int)__ffsll(b) - 1; bool h1 = (b != 0ULL); b &= b - 1;
        int ja = h0 ? lane * 48 + p0 : 0;
        int jb = h1 ? lane * 48 + p1 : 0;
        u64 na = s_node[ja];                    // safe reads, issued together
        u64 nb = s_node[jb];
        float sa = s_elog[ja];
        float sb = s_elog[jb];
        unsigned hia = (unsigned)(na >> 32);
        unsigned hib = (unsigned)(nb >> 32);
        int wa_slot = h0 ? ja : NN;             // predicated via dummy slot (no branch)
        int wb_slot = h1 ? jb : NN + 1;
        ((unsigned*)&s_node[wa_slot])[1] = hia - 1u;
        ((unsigned*)&s_node[wb_slot])[1] = hib - 1u;
        bool ea = h0 && (hia == 1u);
        bool eb = h1 && (hib == 1u);
        u64 pa = ea ? (((na & 0xFFFFFFFFULL) << 32) | (unsigned)(~ja)) : 0ULL;
        u64 pb = eb ? (((nb & 0xFFFFFFFFULL) << 32) | (unsigned)(~jb)) : 0ULL;
        float selog_add = (ea ? sa : 0.f) + (eb ? sb : 0.f);

        // merge insertions (avg ~1/iter): flat ballot rounds
        u64 ba = __ballot(pa != 0ULL);
        while (ba) {
            int src = (int)__ffsll(ba) - 1; ba &= ba - 1;
            unsigned klo = (unsigned)rdlane((int)(unsigned)pa, src);
            unsigned khi = (unsigned)rdlane((int)(unsigned)(pa >> 32), src);
            u64 kin = ((u64)khi << 32) | klo;
            int j3 = (int)~klo;
            int gj = j3 / 48;
            if (lane == gj && kin > mykey) mykey = kin;
        }
        u64 bb2 = __ballot(pb != 0ULL);
        while (bb2) {
            int src = (int)__ffsll(bb2) - 1; bb2 &= bb2 - 1;
            unsigned klo = (unsigned)rdlane((int)(unsigned)pb, src);
            unsigned khi = (unsigned)rdlane((int)(unsigned)(pb >> 32), src);
            u64 kin = ((u64)khi << 32) | klo;
            int j3 = (int)~klo;
            int gj = j3 / 48;
            if (lane == gj && kin > mykey) mykey = kin;
        }
        // rare fallback: lanes with >=3 bits
        if (__ballot(b != 0ULL)) {
            u64 pend = 0ULL;
            while (true) {
                if (pend == 0ULL) {
                    while (b) {
                        int p = (int)__ffsll(b) - 1; b &= b - 1;
                        int j2 = lane * 48 + p;
                        u64 nw2 = s_node[j2];
                        unsigned hi = (unsigned)(nw2 >> 32);
                        ((unsigned*)&s_node[j2])[1] = hi - 1u;
                        if (hi == 1u) {
                            pend = ((nw2 & 0xFFFFFFFFULL) << 32) | (unsigned)(~j2);
                            break;
                        }
                    }
                }
                u64 ab = __ballot(pend != 0ULL);
                if (ab == 0ULL) break;
                int src = (int)__ffsll(ab) - 1;
                unsigned klo = (unsigned)rdlane((int)(unsigned)pend, src);
                unsigned khi = (unsigned)rdlane((int)(unsigned)(pend >> 32), src);
                u64 kin = ((u64)khi << 32) | klo;
                int j3 = (int)~klo;
                int gj = j3 / 48;
                if (lane == gj && kin > mykey) mykey = kin;
                S += s_elog[j3];
                if (lane == src) pend = 0ULL;
            }
        }

        // S update (off-chain; consumed only by next iter's record)
        float add = wsum_f32(selog_add);
        S += __int_as_float(rdlane(__float_as_int(add), 63));
        S -= elog_sel;

        // ---- tournament -> next winner ----
        {
            unsigned vhi = (unsigned)(mykey >> 32);
            unsigned mx = (unsigned)rdlane((int)wmax_u32(vhi), 63);
            u64 ball = __ballot(vhi == mx);
            int gw = (int)__ffsll(ball) - 1;
            unsigned lo = (unsigned)rdlane((int)(unsigned)mykey, gw);
            k = ((u64)mx << 32) | lo;
        }
        // prefetch next winner's window (used ~full iteration later)
        wb = packedT64[(size_t)(~(unsigned)k) * 64 + lane];
    }

    // ---- epilogue: all log_probs in parallel ----
    for (int i = lane; i < NN; i += 64) {
        unsigned si = s_ssel[i];
        float Si = s_slog[i];
        out[si] = -logf((1.0f / s_elog[si]) * Si + 1e-10f);
    }
}

extern "C" void kernel_launch(void* const* d_in, const int* in_sizes, int n_in,
                              void* d_out, int out_size, void* d_ws, size_t ws_size,
                              hipStream_t stream) {
    const float* logits = (const float*)d_in[0];
    const float* adj    = (const float*)d_in[1];
    const float* unif   = (const float*)d_in[2];
    float* out = (float*)d_out;

    char* ws = (char*)d_ws;
    float*    rowsum    = (float*)(ws + 0);                  // 12 KB
    unsigned* packedT   = (unsigned*)(ws + 16384);           // 1,179,648 B
    u64*      packedT64 = (u64*)(ws + 1196032);              // 1,572,864 B
    float*    elog      = (float*)(ws + 2768896);
    unsigned* keyenc    = (unsigned*)(ws + 2781184);
    int*      indeg     = (int*)   (ws + 2793472);           // ends 2,805,760

    rowsum_kernel<<<NN, 256, 0, stream>>>(adj, rowsum);
    pack_kernel<<<dim3(NN / 256, NW), 256, 0, stream>>>(adj, packedT);
    repack_kernel<<<NN * 64 / 256, 256, 0, stream>>>(packedT, packedT64);
    gumbel_kernel<<<NN / 256, 256, 0, stream>>>(logits, unif, rowsum, out,
                                                elog, keyenc, indeg);
    topo_kernel<<<1, 256, 0, stream>>>(elog, keyenc, indeg, packedT64, out);
}